// Round 8
// baseline (1262.209 us; speedup 1.0000x reference)
//
#include <hip/hip_runtime.h>
#include <cstdint>
#include <cstddef>

// ---------------------------------------------------------------------------
// TGN transformer attention layer, MI355X (gfx950).
//   k_prep  : pack k_q weights to f16; bq_eff (time-ones folded)
//   k_wcomp : Weff = [Wk;Wv] @ Wkv (f32) -> f16 fragment-packed; beff
//   CSR     : hist/scan/scatter over dst
//   k_q     : D rows: Q_ori -> Qh(f32), Kh_self, Vh_self (f16)
//   k_kv    : single GEMM C[E x 512] = X[E x 384] @ Weff^T + beff.
//             Persistent 8-wave blocks; FULL A-tile (12 chunks) staged in LDS
//             per tile; 12-chunk MFMA loop with NO internal barriers (B dbuf
//             in VGPRs from L2); next-tile loads issued under compute.
//             Epilogue: 4 passes of 32 rows x 512 cols, LDS stride 520.
//   k_agg   : per-dst wave: segment softmax + weighted V sum + relu + LN
// ---------------------------------------------------------------------------

typedef _Float16 f16_t;
typedef _Float16 f16x8 __attribute__((ext_vector_type(8)));
typedef _Float16 f16x4 __attribute__((ext_vector_type(4)));
typedef float    f32x4 __attribute__((ext_vector_type(4)));

#define MFMA16(a, b, c) __builtin_amdgcn_mfma_f32_16x16x32_f16(a, b, c, 0, 0, 0)

#define BARRIER()                                         \
  do {                                                    \
    asm volatile("s_waitcnt lgkmcnt(0)" ::: "memory");    \
    __builtin_amdgcn_sched_barrier(0);                    \
    __builtin_amdgcn_s_barrier();                         \
    __builtin_amdgcn_sched_barrier(0);                    \
  } while (0)

static __device__ __forceinline__ f32x4 zero4() {
  f32x4 v; v[0] = 0.f; v[1] = 0.f; v[2] = 0.f; v[3] = 0.f; return v;
}

// w_j = 10^(-9 j / 99)  ->  exp2(j * (-9*log2(10)/99))
#define TIMEW_LOG2 (-0.30199346317157837f)

// ---------------------------------------------------------------------------
__global__ void k_prep(const float* __restrict__ wq_lin,
                       const float* __restrict__ bq_lin,
                       const float* __restrict__ wq,
                       const float* __restrict__ wk,
                       const float* __restrict__ wv,
                       f16_t* __restrict__ wq1,
                       f16_t* __restrict__ w3,
                       float* __restrict__ bqe) {
  int i = blockIdx.x * 256 + threadIdx.x;
  if (i < 32768) {
    int o = i >> 7, k = i & 127;
    wq1[i] = (f16_t)wq_lin[o * 228 + k];
  } else if (i < 229376) {
    int j = i - 32768;
    int r = j >> 8, k = j & 255;
    const float* src = (r < 256) ? wq : ((r < 512) ? wk : wv);
    w3[j] = (f16_t)src[(r & 255) * 256 + k];
  } else if (i < 229632) {
    int o = i - 229376;
    float s = bq_lin[o];
    for (int j = 0; j < 100; ++j) s += wq_lin[o * 228 + 128 + j];
    bqe[o] = s;
  }
}

// ---------------------------------------------------------------------------
// k_wcomp: Weff[oc][c] = sum_m W23[oc][m] * Wkv[m][c]; packed:
//   idx = kc*16384 + g*4096 + oc*8 + j   (c = kc*32 + g*8 + j)
// ---------------------------------------------------------------------------
__global__ __launch_bounds__(384) void k_wcomp(
    const float* __restrict__ wkv_lin, const float* __restrict__ bkv,
    const float* __restrict__ wk, const float* __restrict__ bk,
    const float* __restrict__ wv, const float* __restrict__ bv,
    f16_t* __restrict__ weffp, float* __restrict__ beff) {
  __shared__ float wrow[256];
  const int oc = blockIdx.x;
  const float* src = (oc < 256) ? (wk + (size_t)oc * 256)
                                : (wv + (size_t)(oc - 256) * 256);
  const int t = threadIdx.x;
  if (t < 256) wrow[t] = src[t];
  __syncthreads();

  float acc = 0.f;
  if (t < 356) {
#pragma unroll 4
    for (int m = 0; m < 256; ++m) acc += wrow[m] * wkv_lin[(size_t)m * 356 + t];
  }
  int kc = t >> 5, g = (t >> 3) & 3, j = t & 7;
  weffp[(size_t)kc * 16384 + g * 4096 + oc * 8 + j] = (f16_t)acc;

  if (t == 0) {
    float b = (oc < 256) ? bk[oc] : bv[oc - 256];
    for (int m = 0; m < 256; ++m) b += wrow[m] * bkv[m];
    beff[oc] = b;
  }
}

// ---------------------------------------------------------------------------
// CSR build
// ---------------------------------------------------------------------------
__global__ void k_hist(const int* __restrict__ dst, int* __restrict__ rs, int E) {
  int e = blockIdx.x * 256 + threadIdx.x;
  if (e < E) atomicAdd(&rs[dst[e] + 1], 1);
}

__global__ void k_scan(int* __restrict__ rs, int* __restrict__ cur, int D) {
  __shared__ int sd[1024];
  __shared__ int srun;
  const int t = threadIdx.x;
  if (t == 0) srun = 0;
  __syncthreads();
  for (int base = 0; base < D; base += 1024) {
    const int i = base + t;
    int c = (i < D) ? rs[i + 1] : 0;
    sd[t] = c;
    __syncthreads();
    for (int off = 1; off < 1024; off <<= 1) {
      int v = (t >= off) ? sd[t - off] : 0;
      __syncthreads();
      sd[t] += v;
      __syncthreads();
    }
    const int incl = sd[t];
    const int run = srun;
    __syncthreads();
    if (i < D) {
      cur[i] = run + incl - c;
      rs[i + 1] = run + incl;
    }
    if (t == 1023) srun = run + sd[1023];
    __syncthreads();
  }
}

__global__ void k_scatter(const int* __restrict__ dst, int* __restrict__ cur,
                          int* __restrict__ csr, int E) {
  int e = blockIdx.x * 256 + threadIdx.x;
  if (e < E) {
    int pos = atomicAdd(&cur[dst[e]], 1);
    csr[pos] = e;
  }
}

__global__ void k_sentinel(float* __restrict__ o, int n) {
  int i = blockIdx.x * 256 + threadIdx.x;
  if (i < n) o[i] = 1e30f;
}

// ---------------------------------------------------------------------------
// k_q: 64 dst rows per block, 8 waves (small kernel, D=25k rows).
// ---------------------------------------------------------------------------
__global__ __launch_bounds__(512) void k_q(
    const float* __restrict__ h, const float* __restrict__ bqe,
    const float* __restrict__ bq, const float* __restrict__ bk,
    const float* __restrict__ bv, const f16_t* __restrict__ wq1,
    const f16_t* __restrict__ w3, float* __restrict__ qhd,
    f16_t* __restrict__ khs, f16_t* __restrict__ vhs, int D) {
  __shared__ f16_t sm[64 * 256];
  f16_t* xs = sm;
  f16_t* ks = sm;
  const int tid = threadIdx.x;
  const int dbase = blockIdx.x * 64;

  {
    const int r = tid >> 3, q = tid & 7;
    const int dd = min(dbase + r, D - 1);
    const int sw = r & 7;
    const float* p = h + (size_t)dd * 128 + q * 16;
#pragma unroll
    for (int u = 0; u < 2; ++u) {
      float4 v0 = *(const float4*)(p + u * 8);
      float4 v1 = *(const float4*)(p + u * 8 + 4);
      f16x8 w8;
      w8[0] = (f16_t)v0.x; w8[1] = (f16_t)v0.y; w8[2] = (f16_t)v0.z; w8[3] = (f16_t)v0.w;
      w8[4] = (f16_t)v1.x; w8[5] = (f16_t)v1.y; w8[6] = (f16_t)v1.z; w8[7] = (f16_t)v1.w;
      *(f16x8*)&xs[r * 128 + (((2 * q + u) ^ sw) << 3)] = w8;
    }
  }
  __syncthreads();

  const int lane = tid & 63;
  const int wv_ = tid >> 6;
  const int m16 = lane & 15;
  const int g = lane >> 4;

  f32x4 acc1[4][2];
#pragma unroll
  for (int mt = 0; mt < 4; ++mt)
#pragma unroll
    for (int nt = 0; nt < 2; ++nt) acc1[mt][nt] = zero4();

#pragma unroll
  for (int kt = 0; kt < 4; ++kt) {
    f16x8 a[4];
#pragma unroll
    for (int mt = 0; mt < 4; ++mt) {
      int row = mt * 16 + m16;
      a[mt] = *(const f16x8*)&xs[row * 128 + ((((kt << 2) + g) ^ (row & 7)) << 3)];
    }
#pragma unroll
    for (int nt = 0; nt < 2; ++nt) {
      int col = wv_ * 32 + nt * 16 + m16;
      f16x8 b = *(const f16x8*)&wq1[(size_t)col * 128 + (kt << 5) + (g << 3)];
#pragma unroll
      for (int mt = 0; mt < 4; ++mt) acc1[mt][nt] = MFMA16(a[mt], b, acc1[mt][nt]);
    }
  }
  __syncthreads();

#pragma unroll
  for (int nt = 0; nt < 2; ++nt) {
    int col = wv_ * 32 + nt * 16 + m16;
    float bias = bqe[col];
#pragma unroll
    for (int mt = 0; mt < 4; ++mt)
#pragma unroll
      for (int j = 0; j < 4; ++j) {
        int row = mt * 16 + (g << 2) + j;
        ks[row * 256 + ((((col >> 3) ^ (row & 7)) << 3)) + (col & 7)] =
            (f16_t)(acc1[mt][nt][j] + bias);
      }
  }
  __syncthreads();

#pragma unroll
  for (int p = 0; p < 3; ++p) {
    const f16_t* wsec = w3 + ((size_t)p << 16);
    const float* bsec = (p == 0) ? bq : ((p == 1) ? bk : bv);
    f32x4 acc[4][2];
#pragma unroll
    for (int mt = 0; mt < 4; ++mt)
#pragma unroll
      for (int nt = 0; nt < 2; ++nt) acc[mt][nt] = zero4();
#pragma unroll
    for (int kt = 0; kt < 8; ++kt) {
      f16x8 a[4];
#pragma unroll
      for (int mt = 0; mt < 4; ++mt) {
        int row = mt * 16 + m16;
        a[mt] = *(const f16x8*)&ks[row * 256 + ((((kt << 2) + g) ^ (row & 7)) << 3)];
      }
#pragma unroll
      for (int nt = 0; nt < 2; ++nt) {
        int col = wv_ * 32 + nt * 16 + m16;
        f16x8 b = *(const f16x8*)&wsec[(size_t)col * 256 + (kt << 5) + (g << 3)];
#pragma unroll
        for (int mt = 0; mt < 4; ++mt) acc[mt][nt] = MFMA16(a[mt], b, acc[mt][nt]);
      }
    }
#pragma unroll
    for (int nt = 0; nt < 2; ++nt) {
      int col = wv_ * 32 + nt * 16 + m16;
      float bias = bsec[col];
#pragma unroll
      for (int mt = 0; mt < 4; ++mt)
#pragma unroll
        for (int j = 0; j < 4; ++j) {
          int row = mt * 16 + (g << 2) + j;
          int dd = dbase + row;
          if (dd < D) {
            float val = acc[mt][nt][j] + bias;
            if (p == 0)
              qhd[(size_t)dd * 256 + col] = val;
            else if (p == 1)
              khs[(size_t)dd * 256 + col] = (f16_t)val;
            else
              vhs[(size_t)dd * 256 + col] = (f16_t)val;
          }
        }
    }
  }
}

// ---------------------------------------------------------------------------
// k_kv: C[E x 512] = X[E x 384] @ Weff^T + beff
//   Persistent grid (256 blocks), 512 threads = 8 waves (wm 2 x wn 4),
//   wave-tile 64x128 (acc 4x8).  Per tile: FULL A (128x384 f16) staged in
//   LDS fragment-packed [chunk][g][row][8]; 12-chunk MFMA loop barrier-free;
//   B (weffp, L2-resident) dbuf'd in VGPRs one chunk ahead; next-tile global
//   loads issued under compute.  Epilogue: 4 passes of 32 rows x 512 cols
//   through LDS (stride 520 f16) -> coalesced full-line stores.
//   LDS: A 96 KB + epi 32.5 KB = 129 KB -> 1 block/CU, 2 waves/SIMD.
// ---------------------------------------------------------------------------
__global__ __launch_bounds__(512, 2) void k_kv(
    const float* __restrict__ h, const float* __restrict__ f,
    const float* __restrict__ dt, const f16_t* __restrict__ weffp,
    const float* __restrict__ beff, f16_t* __restrict__ khg,
    f16_t* __restrict__ vhg, int D, int E, int ntiles) {
  __shared__ __align__(16) unsigned char smem[132096];  // 96K A + 33.8K epi

  const int tid = threadIdx.x;
  const int row = tid >> 2, q = tid & 3;     // staging: 128 rows x 4 octets
  const int lane = tid & 63, wid = tid >> 6;
  const int wm = wid >> 2, wn = wid & 3;
  const int m16 = lane & 15, g = lane >> 4;

  f16_t* ep = (f16_t*)(smem + 98304);        // [32][520] f16 = 33280 B

  // per-wave bias registers (cols wn*128 + n*16 + m16)
  float brg[8];
#pragma unroll
  for (int n = 0; n < 8; ++n) brg[n] = beff[wn * 128 + n * 16 + m16];

  const float wq0 = exp2f(TIMEW_LOG2 * (float)(q * 8));
  const f16_t* wb = weffp + (size_t)g * 4096 + ((size_t)(wn * 128 + m16) << 3);

  // A chunk c at smem + c*8192, byte offset q*2048 + row*16 (write) /
  // g*2048 + r*16 (read) -- conflict-free by construction.
  auto wrA = [&](int c, float4 a, float4 b) {
    f16x8 w;
    w[0] = (f16_t)a.x; w[1] = (f16_t)a.y; w[2] = (f16_t)a.z; w[3] = (f16_t)a.w;
    w[4] = (f16_t)b.x; w[5] = (f16_t)b.y; w[6] = (f16_t)b.z; w[7] = (f16_t)b.w;
    *(f16x8*)(smem + c * 8192 + q * 2048 + row * 16) = w;
  };
  auto ldB = [&](int c, f16x8* d) {
    const f16_t* p = wb + (size_t)c * 16384;
#pragma unroll
    for (int n = 0; n < 8; ++n) d[n] = *(const f16x8*)(p + n * 128);
  };

  float4 hv[8];
  float dtv;

  int t = blockIdx.x;
  {  // prologue: load h(t0), dt(t0)
    int ae = min(t * 128 + row, E - 1);
    const float* hr = h + (size_t)(D + ae) * 128 + q * 8;
#pragma unroll
    for (int u = 0; u < 4; ++u) {
      hv[2 * u]     = *(const float4*)(hr + u * 32);
      hv[2 * u + 1] = *(const float4*)(hr + u * 32 + 4);
    }
    dtv = dt[ae];
  }

  for (; t < ntiles; t += gridDim.x) {
    // ---- stage h chunks 0-3 and time chunks 8-11
#pragma unroll
    for (int kc = 0; kc < 4; ++kc) wrA(kc, hv[2 * kc], hv[2 * kc + 1]);
#pragma unroll
    for (int kc = 8; kc < 12; ++kc) {
      float4 a, b;
#pragma unroll
      for (int jj = 0; jj < 8; ++jj) {
        int cc = (kc - 8) * 32 + q * 8 + jj;
        float w = wq0 * exp2f(TIMEW_LOG2 * (float)((kc - 8) * 32 + jj));
        float val = (cc < 100) ? __cosf(dtv * w) : 0.f;
        if (jj < 4) ((float*)&a)[jj] = val; else ((float*)&b)[jj - 4] = val;
      }
      wrA(kc, a, b);
    }
    // ---- issue f(t) loads (consumed mid-loop)
    {
      int ae = min(t * 128 + row, E - 1);
      const float* fr = f + (size_t)ae * 128 + q * 8;
#pragma unroll
      for (int u = 0; u < 4; ++u) {
        hv[2 * u]     = *(const float4*)(fr + u * 32);
        hv[2 * u + 1] = *(const float4*)(fr + u * 32 + 4);
      }
    }
    BARRIER();

    f32x4 acc[4][8];
#pragma unroll
    for (int mt = 0; mt < 4; ++mt)
#pragma unroll
      for (int n = 0; n < 8; ++n) acc[mt][n] = zero4();

    f16x8 bb0[8], bb1[8];
    auto doChunk = [&](int c, f16x8* bbuf) {
      const unsigned char* Ac = smem + c * 8192;
#pragma unroll
      for (int mt = 0; mt < 4; ++mt) {
        f16x8 afr =
            *(const f16x8*)(Ac + g * 2048 + (wm * 64 + mt * 16 + m16) * 16);
#pragma unroll
        for (int n = 0; n < 8; ++n) acc[mt][n] = MFMA16(afr, bbuf[n], acc[mt][n]);
      }
    };

    ldB(0, bb0);
    ldB(1, bb1); doChunk(0, bb0);
    ldB(2, bb0); doChunk(1, bb1);
    ldB(3, bb1); doChunk(2, bb0);
    ldB(4, bb0); doChunk(3, bb1);

    // ---- mid wedge: stage f chunks 4-7; issue h(t+stride) loads
#pragma unroll
    for (int kc = 4; kc < 8; ++kc)
      wrA(kc, hv[2 * (kc - 4)], hv[2 * (kc - 4) + 1]);
    {
      int ae = min((t + (int)gridDim.x) * 128 + row, E - 1);
      const float* hr = h + (size_t)(D + ae) * 128 + q * 8;
#pragma unroll
      for (int u = 0; u < 4; ++u) {
        hv[2 * u]     = *(const float4*)(hr + u * 32);
        hv[2 * u + 1] = *(const float4*)(hr + u * 32 + 4);
      }
      dtv = dt[ae];
    }
    BARRIER();

    ldB(5, bb1);  doChunk(4, bb0);
    ldB(6, bb0);  doChunk(5, bb1);
    ldB(7, bb1);  doChunk(6, bb0);
    ldB(8, bb0);  doChunk(7, bb1);
    ldB(9, bb1);  doChunk(8, bb0);
    ldB(10, bb0); doChunk(9, bb1);
    ldB(11, bb1); doChunk(10, bb0);
    doChunk(11, bb1);

    // ---- epilogue: 4 passes of 32 rows x 512 cols via LDS (stride 520)
    //   pass p: block rows [p*32, p*32+32) = wave wm==p>>1, mt in {2(p&1),+1}
#pragma unroll
    for (int p = 0; p < 4; ++p) {
      if (wm == (p >> 1)) {
        const int mtb = (p & 1) * 2;
#pragma unroll
        for (int n = 0; n < 8; ++n) {
          const int col = wn * 128 + n * 16 + m16;
#pragma unroll
          for (int mo = 0; mo < 2; ++mo)
#pragma unroll
            for (int j = 0; j < 4; ++j) {
              const int r = mo * 16 + g * 4 + j;
              ep[r * 520 + col] = (f16_t)(acc[mtb + mo][n][j] + brg[n]);
            }
        }
      }
      BARRIER();
#pragma unroll
      for (int sweep = 0; sweep < 4; ++sweep) {
        const int idx = sweep * 4096 + tid * 8;
        const int r = idx >> 9, c = idx & 511;
        const int e = t * 128 + p * 32 + r;
        if (e < E) {
          f16x8 v = *(const f16x8*)&ep[r * 520 + c];
          f16_t* ob = (c < 256) ? khg : vhg;
          *(f16x8*)&ob[(size_t)e * 256 + (c & 255)] = v;
        }
      }
      if (p < 3) BARRIER();
    }
  }
}

// ---------------------------------------------------------------------------
// k_agg: one wave per dst node (csr gather). Softmax without max-shift.
// ---------------------------------------------------------------------------
__global__ __launch_bounds__(256) void k_agg(
    const float* __restrict__ qhd, const f16_t* __restrict__ khs,
    const f16_t* __restrict__ vhs, const f16_t* __restrict__ khg,
    const f16_t* __restrict__ vhg, const int* __restrict__ rs,
    const int* __restrict__ csr, const float* __restrict__ lng,
    const float* __restrict__ lnb, float* __restrict__ out, int D) {
  const int lane = threadIdx.x & 63;
  const int d = blockIdx.x * 4 + (threadIdx.x >> 6);
  if (d >= D) return;
  const int c0 = lane * 4;

  float qh0, qh1, qh2, qh3;
  {
    float4 v = *(const float4*)(qhd + (size_t)d * 256 + c0);
    qh0 = v.x; qh1 = v.y; qh2 = v.z; qh3 = v.w;
  }

  float den, a0, a1, a2, a3;
  {
    f16x4 ku = *(const f16x4*)(khs + (size_t)d * 256 + c0);
    f16x4 vu = *(const f16x4*)(vhs + (size_t)d * 256 + c0);
    float s = qh0 * (float)ku[0] + qh1 * (float)ku[1] + qh2 * (float)ku[2] + qh3 * (float)ku[3];
    s += __shfl_xor(s, 1); s += __shfl_xor(s, 2); s += __shfl_xor(s, 4);
    s = (s > 0.f) ? s : 0.2f * s;
    float ee = __expf(s);
    den = ee;
    a0 = ee * (float)vu[0]; a1 = ee * (float)vu[1];
    a2 = ee * (float)vu[2]; a3 = ee * (float)vu[3];
  }

  const int beg = rs[d], end = rs[d + 1];
  f16x4 kN, vN;
  if (beg < end) {
    int e = csr[beg];
    kN = *(const f16x4*)(khg + (size_t)e * 256 + c0);
    vN = *(const f16x4*)(vhg + (size_t)e * 256 + c0);
  }
  for (int idx = beg; idx < end; ++idx) {
    f16x4 ku = kN, vu = vN;
    if (idx + 1 < end) {
      int e = csr[idx + 1];
      kN = *(const f16x4*)(khg + (size_t)e * 256 + c0);
      vN = *(const f16x4*)(vhg + (size_t)e * 256 + c0);
    }
    float s = qh0 * (float)ku[0] + qh1 * (float)ku[1] + qh2 * (float)ku[2] + qh3 * (float)ku[3];
    s += __shfl_xor(s, 1); s += __shfl_xor(s, 2); s += __shfl_xor(s, 4);
    s = (s > 0.f) ? s : 0.2f * s;
    float ee = __expf(s);
    den += ee;
    a0 = fmaf(ee, (float)vu[0], a0); a1 = fmaf(ee, (float)vu[1], a1);
    a2 = fmaf(ee, (float)vu[2], a2); a3 = fmaf(ee, (float)vu[3], a3);
  }

  float x0 = fmaxf(a0 / den, 0.f), x1 = fmaxf(a1 / den, 0.f);
  float x2 = fmaxf(a2 / den, 0.f), x3 = fmaxf(a3 / den, 0.f);

  float s1 = x0 + x1 + x2 + x3;
#pragma unroll
  for (int m = 1; m < 64; m <<= 1) s1 += __shfl_xor(s1, m);
  float mu = s1 * (1.f / 256.f);
  float d0 = x0 - mu, d1 = x1 - mu, d2 = x2 - mu, d3 = x3 - mu;
  float s2 = d0 * d0 + d1 * d1 + d2 * d2 + d3 * d3;
#pragma unroll
  for (int m = 1; m < 64; m <<= 1) s2 += __shfl_xor(s2, m);
  float rstd = rsqrtf(s2 * (1.f / 256.f) + 1e-5f);

  float4 gg = *(const float4*)(lng + c0);
  float4 bb = *(const float4*)(lnb + c0);
  float4 o;
  o.x = d0 * rstd * gg.x + bb.x;
  o.y = d1 * rstd * gg.y + bb.y;
  o.z = d2 * rstd * gg.z + bb.z;
  o.w = d3 * rstd * gg.w + bb.w;
  *(float4*)(out + (size_t)d * 256 + c0) = o;
}

// ---------------------------------------------------------------------------
extern "C" void kernel_launch(void* const* d_in, const int* in_sizes, int n_in,
                              void* d_out, int out_size, void* d_ws,
                              size_t ws_size, hipStream_t stream) {
  const float* h       = (const float*)d_in[0];
  const float* f       = (const float*)d_in[1];
  const float* dt      = (const float*)d_in[2];
  const float* wq_lin  = (const float*)d_in[3];
  const float* bq_lin  = (const float*)d_in[4];
  const float* wkv_lin = (const float*)d_in[5];
  const float* bkv_lin = (const float*)d_in[6];
  const float* wq      = (const float*)d_in[7];
  const float* bq      = (const float*)d_in[8];
  const float* wk      = (const float*)d_in[9];
  const float* bk      = (const float*)d_in[10];
  const float* wv      = (const float*)d_in[11];
  const float* bv      = (const float*)d_in[12];
  const float* lng     = (const float*)d_in[13];
  const float* lnb     = (const float*)d_in[14];
  const int*   dst     = (const int*)d_in[15];

  const int S = in_sizes[0] / 128;
  const int E = in_sizes[2];
  const int D = S - E;
  float* out = (float*)d_out;

  char* p = (char*)d_ws;
  size_t off = 0;
  auto take = [&](size_t bytes) -> char* {
    char* r = p + off;
    off += (bytes + 255) & ~(size_t)255;
    return r;
  };
  f16_t* wq1   = (f16_t*)take((size_t)32768 * 2);
  f16_t* w3    = (f16_t*)take((size_t)196608 * 2);
  float* bqe   = (float*)take((size_t)256 * 4);
  f16_t* weffp = (f16_t*)take((size_t)196608 * 2);
  float* beff  = (float*)take((size_t)512 * 4);
  float* qhd   = (float*)take((size_t)D * 256 * 4);
  f16_t* khs   = (f16_t*)take((size_t)D * 256 * 2);
  f16_t* vhs   = (f16_t*)take((size_t)D * 256 * 2);
  f16_t* khg   = (f16_t*)take((size_t)E * 256 * 2);
  f16_t* vhg   = (f16_t*)take((size_t)E * 256 * 2);
  int*   rs    = (int*)  take((size_t)(D + 1) * 4);
  int*   cur   = (int*)  take((size_t)D * 4);
  int*   csr   = (int*)  take((size_t)E * 4);

  if (off > ws_size) {
    k_sentinel<<<(out_size + 255) / 256, 256, 0, stream>>>(out, out_size);
    return;
  }

  const int ntiles = (E + 127) / 128;

  hipMemsetAsync(rs, 0, (size_t)(D + 1) * 4, stream);
  k_prep<<<898, 256, 0, stream>>>(wq_lin, bq_lin, wq, wk, wv, wq1, w3, bqe);
  k_wcomp<<<512, 384, 0, stream>>>(wkv_lin, bkv_lin, wk, bk, wv, bv, weffp,
                                   beff);
  k_hist<<<(E + 255) / 256, 256, 0, stream>>>(dst, rs, E);
  k_scan<<<1, 1024, 0, stream>>>(rs, cur, D);
  k_scatter<<<(E + 255) / 256, 256, 0, stream>>>(dst, cur, csr, E);
  k_q<<<(D + 63) / 64, 512, 0, stream>>>(h, bqe, bq, bk, bv, wq1, w3, qhd, khs,
                                         vhs, D);
  k_kv<<<256, 512, 0, stream>>>(h, f, dt, weffp, beff, khg, vhg, D, E, ntiles);
  k_agg<<<(D + 3) / 4, 256, 0, stream>>>(qhd, khs, vhs, khg, vhg, rs, csr, lng,
                                         lnb, out, D);
}

// Round 9
// 731.059 us; speedup vs baseline: 1.7265x; 1.7265x over previous
//
#include <hip/hip_runtime.h>
#include <cstdint>
#include <cstddef>

// ---------------------------------------------------------------------------
// TGN transformer attention layer, MI355X (gfx950).
//   k_prep  : pack k_q weights to f16; bq_eff (time-ones folded)
//   k_wcomp : Weff = [Wk;Wv] @ Wkv (f32) -> f16 fragment-packed; beff
//   CSR     : hist/scan/scatter over dst
//   k_q     : D rows: Q_ori -> Qh(f32), Kh_self, Vh_self (f16)
//   k_kv    : GEMM C[E x 512] = X[E x 384] @ Weff^T + beff  (round-6 proven
//             structure: B global->VGPR dbuf, A reg-staged f16 stride-80 LDS,
//             lgkm-only barriers).  Epilogue pass 0 now computes
//             att[e][h] = exp(leaky(Qh[dst[e]] . Kh[e])) from LDS-staged Kh
//             (Kh never hits global); pass 1 stores Vh coalesced.
//   k_agg   : per-dst wave: att + V gather, weighted sum + relu + LN
// ---------------------------------------------------------------------------

typedef _Float16 f16_t;
typedef _Float16 f16x8 __attribute__((ext_vector_type(8)));
typedef _Float16 f16x4 __attribute__((ext_vector_type(4)));
typedef float    f32x4 __attribute__((ext_vector_type(4)));

#define MFMA16(a, b, c) __builtin_amdgcn_mfma_f32_16x16x32_f16(a, b, c, 0, 0, 0)

#define BARRIER()                                         \
  do {                                                    \
    asm volatile("s_waitcnt lgkmcnt(0)" ::: "memory");    \
    __builtin_amdgcn_sched_barrier(0);                    \
    __builtin_amdgcn_s_barrier();                         \
    __builtin_amdgcn_sched_barrier(0);                    \
  } while (0)

static __device__ __forceinline__ f32x4 zero4() {
  f32x4 v; v[0] = 0.f; v[1] = 0.f; v[2] = 0.f; v[3] = 0.f; return v;
}

// w_j = 10^(-9 j / 99)  ->  exp2(j * (-9*log2(10)/99))
#define TIMEW_LOG2 (-0.30199346317157837f)

// ---------------------------------------------------------------------------
__global__ void k_prep(const float* __restrict__ wq_lin,
                       const float* __restrict__ bq_lin,
                       const float* __restrict__ wq,
                       const float* __restrict__ wk,
                       const float* __restrict__ wv,
                       f16_t* __restrict__ wq1,
                       f16_t* __restrict__ w3,
                       float* __restrict__ bqe) {
  int i = blockIdx.x * 256 + threadIdx.x;
  if (i < 32768) {
    int o = i >> 7, k = i & 127;
    wq1[i] = (f16_t)wq_lin[o * 228 + k];
  } else if (i < 229376) {
    int j = i - 32768;
    int r = j >> 8, k = j & 255;
    const float* src = (r < 256) ? wq : ((r < 512) ? wk : wv);
    w3[j] = (f16_t)src[(r & 255) * 256 + k];
  } else if (i < 229632) {
    int o = i - 229376;
    float s = bq_lin[o];
    for (int j = 0; j < 100; ++j) s += wq_lin[o * 228 + 128 + j];
    bqe[o] = s;
  }
}

// ---------------------------------------------------------------------------
// k_wcomp: Weff[oc][c] = sum_m W23[oc][m] * Wkv[m][c]; packed:
//   idx = kc*16384 + g*4096 + oc*8 + j   (c = kc*32 + g*8 + j)
// ---------------------------------------------------------------------------
__global__ __launch_bounds__(384) void k_wcomp(
    const float* __restrict__ wkv_lin, const float* __restrict__ bkv,
    const float* __restrict__ wk, const float* __restrict__ bk,
    const float* __restrict__ wv, const float* __restrict__ bv,
    f16_t* __restrict__ weffp, float* __restrict__ beff) {
  __shared__ float wrow[256];
  const int oc = blockIdx.x;
  const float* src = (oc < 256) ? (wk + (size_t)oc * 256)
                                : (wv + (size_t)(oc - 256) * 256);
  const int t = threadIdx.x;
  if (t < 256) wrow[t] = src[t];
  __syncthreads();

  float acc = 0.f;
  if (t < 356) {
#pragma unroll 4
    for (int m = 0; m < 256; ++m) acc += wrow[m] * wkv_lin[(size_t)m * 356 + t];
  }
  int kc = t >> 5, g = (t >> 3) & 3, j = t & 7;
  weffp[(size_t)kc * 16384 + g * 4096 + oc * 8 + j] = (f16_t)acc;

  if (t == 0) {
    float b = (oc < 256) ? bk[oc] : bv[oc - 256];
    for (int m = 0; m < 256; ++m) b += wrow[m] * bkv[m];
    beff[oc] = b;
  }
}

// ---------------------------------------------------------------------------
// CSR build
// ---------------------------------------------------------------------------
__global__ void k_hist(const int* __restrict__ dst, int* __restrict__ rs, int E) {
  int e = blockIdx.x * 256 + threadIdx.x;
  if (e < E) atomicAdd(&rs[dst[e] + 1], 1);
}

__global__ void k_scan(int* __restrict__ rs, int* __restrict__ cur, int D) {
  __shared__ int sd[1024];
  __shared__ int srun;
  const int t = threadIdx.x;
  if (t == 0) srun = 0;
  __syncthreads();
  for (int base = 0; base < D; base += 1024) {
    const int i = base + t;
    int c = (i < D) ? rs[i + 1] : 0;
    sd[t] = c;
    __syncthreads();
    for (int off = 1; off < 1024; off <<= 1) {
      int v = (t >= off) ? sd[t - off] : 0;
      __syncthreads();
      sd[t] += v;
      __syncthreads();
    }
    const int incl = sd[t];
    const int run = srun;
    __syncthreads();
    if (i < D) {
      cur[i] = run + incl - c;
      rs[i + 1] = run + incl;
    }
    if (t == 1023) srun = run + sd[1023];
    __syncthreads();
  }
}

__global__ void k_scatter(const int* __restrict__ dst, int* __restrict__ cur,
                          int* __restrict__ csr, int E) {
  int e = blockIdx.x * 256 + threadIdx.x;
  if (e < E) {
    int pos = atomicAdd(&cur[dst[e]], 1);
    csr[pos] = e;
  }
}

__global__ void k_sentinel(float* __restrict__ o, int n) {
  int i = blockIdx.x * 256 + threadIdx.x;
  if (i < n) o[i] = 1e30f;
}

// ---------------------------------------------------------------------------
// k_q: 64 dst rows per block, 8 waves (small kernel, D=25k rows).
// ---------------------------------------------------------------------------
__global__ __launch_bounds__(512) void k_q(
    const float* __restrict__ h, const float* __restrict__ bqe,
    const float* __restrict__ bq, const float* __restrict__ bk,
    const float* __restrict__ bv, const f16_t* __restrict__ wq1,
    const f16_t* __restrict__ w3, float* __restrict__ qhd,
    f16_t* __restrict__ khs, f16_t* __restrict__ vhs, int D) {
  __shared__ f16_t sm[64 * 256];
  f16_t* xs = sm;
  f16_t* ks = sm;
  const int tid = threadIdx.x;
  const int dbase = blockIdx.x * 64;

  {
    const int r = tid >> 3, q = tid & 7;
    const int dd = min(dbase + r, D - 1);
    const int sw = r & 7;
    const float* p = h + (size_t)dd * 128 + q * 16;
#pragma unroll
    for (int u = 0; u < 2; ++u) {
      float4 v0 = *(const float4*)(p + u * 8);
      float4 v1 = *(const float4*)(p + u * 8 + 4);
      f16x8 w8;
      w8[0] = (f16_t)v0.x; w8[1] = (f16_t)v0.y; w8[2] = (f16_t)v0.z; w8[3] = (f16_t)v0.w;
      w8[4] = (f16_t)v1.x; w8[5] = (f16_t)v1.y; w8[6] = (f16_t)v1.z; w8[7] = (f16_t)v1.w;
      *(f16x8*)&xs[r * 128 + (((2 * q + u) ^ sw) << 3)] = w8;
    }
  }
  __syncthreads();

  const int lane = tid & 63;
  const int wv_ = tid >> 6;
  const int m16 = lane & 15;
  const int g = lane >> 4;

  f32x4 acc1[4][2];
#pragma unroll
  for (int mt = 0; mt < 4; ++mt)
#pragma unroll
    for (int nt = 0; nt < 2; ++nt) acc1[mt][nt] = zero4();

#pragma unroll
  for (int kt = 0; kt < 4; ++kt) {
    f16x8 a[4];
#pragma unroll
    for (int mt = 0; mt < 4; ++mt) {
      int row = mt * 16 + m16;
      a[mt] = *(const f16x8*)&xs[row * 128 + ((((kt << 2) + g) ^ (row & 7)) << 3)];
    }
#pragma unroll
    for (int nt = 0; nt < 2; ++nt) {
      int col = wv_ * 32 + nt * 16 + m16;
      f16x8 b = *(const f16x8*)&wq1[(size_t)col * 128 + (kt << 5) + (g << 3)];
#pragma unroll
      for (int mt = 0; mt < 4; ++mt) acc1[mt][nt] = MFMA16(a[mt], b, acc1[mt][nt]);
    }
  }
  __syncthreads();

#pragma unroll
  for (int nt = 0; nt < 2; ++nt) {
    int col = wv_ * 32 + nt * 16 + m16;
    float bias = bqe[col];
#pragma unroll
    for (int mt = 0; mt < 4; ++mt)
#pragma unroll
      for (int j = 0; j < 4; ++j) {
        int row = mt * 16 + (g << 2) + j;
        ks[row * 256 + ((((col >> 3) ^ (row & 7)) << 3)) + (col & 7)] =
            (f16_t)(acc1[mt][nt][j] + bias);
      }
  }
  __syncthreads();

#pragma unroll
  for (int p = 0; p < 3; ++p) {
    const f16_t* wsec = w3 + ((size_t)p << 16);
    const float* bsec = (p == 0) ? bq : ((p == 1) ? bk : bv);
    f32x4 acc[4][2];
#pragma unroll
    for (int mt = 0; mt < 4; ++mt)
#pragma unroll
      for (int nt = 0; nt < 2; ++nt) acc[mt][nt] = zero4();
#pragma unroll
    for (int kt = 0; kt < 8; ++kt) {
      f16x8 a[4];
#pragma unroll
      for (int mt = 0; mt < 4; ++mt) {
        int row = mt * 16 + m16;
        a[mt] = *(const f16x8*)&ks[row * 256 + ((((kt << 2) + g) ^ (row & 7)) << 3)];
      }
#pragma unroll
      for (int nt = 0; nt < 2; ++nt) {
        int col = wv_ * 32 + nt * 16 + m16;
        f16x8 b = *(const f16x8*)&wsec[(size_t)col * 256 + (kt << 5) + (g << 3)];
#pragma unroll
        for (int mt = 0; mt < 4; ++mt) acc[mt][nt] = MFMA16(a[mt], b, acc[mt][nt]);
      }
    }
#pragma unroll
    for (int nt = 0; nt < 2; ++nt) {
      int col = wv_ * 32 + nt * 16 + m16;
      float bias = bsec[col];
#pragma unroll
      for (int mt = 0; mt < 4; ++mt)
#pragma unroll
        for (int j = 0; j < 4; ++j) {
          int row = mt * 16 + (g << 2) + j;
          int dd = dbase + row;
          if (dd < D) {
            float val = acc[mt][nt][j] + bias;
            if (p == 0)
              qhd[(size_t)dd * 256 + col] = val;
            else if (p == 1)
              khs[(size_t)dd * 256 + col] = (f16_t)val;
            else
              vhs[(size_t)dd * 256 + col] = (f16_t)val;
          }
        }
    }
  }
}

// ---------------------------------------------------------------------------
// k_kv: C[E x 512] = X[E x 384] @ Weff^T + beff   (round-6 proven loop)
//   BM=128, BN=512, BK=32, 1024 threads = 16 waves (wm 2 x wn 8, 64x64/wave)
//   B: weffp fragment-packed, loaded global->VGPR (L2), dbuf 1 chunk ahead.
//   A: f32 global->reg (3 chunks ahead) -> cvt f16 -> ds_write, LDS rows
//      stride 80B, double-buffered.  Chunks 8..11 = cos features in-register.
//   Epilogue pass 0: Kh staged to LDS -> att[e][h]=exp(leaky(Q[dst[e]].Kh))
//   (Kh never stored).  Pass 1: Vh staged -> coalesced global stores.
// ---------------------------------------------------------------------------
__global__ __launch_bounds__(1024, 4) void k_kv(
    const float* __restrict__ h, const float* __restrict__ f,
    const float* __restrict__ dt, const f16_t* __restrict__ weffp,
    const float* __restrict__ beff, const int* __restrict__ dst,
    const float* __restrict__ qhd, float* __restrict__ att,
    f16_t* __restrict__ vhg, int D, int E) {
  __shared__ __align__(16) unsigned char smem[67584];  // 66 KB

  const int tid = threadIdx.x;
  const int ebase = blockIdx.x * 128;
  const int row = tid >> 3, q = tid & 7;
  const int lane = tid & 63, wid = tid >> 6;
  const int wm = wid >> 3, wn = wid & 7;
  const int m16 = lane & 15, g = lane >> 4;
  const int ae = min(ebase + row, E - 1);
  const float dtv = dt[ae];
  const float* hrow = h + (size_t)(D + ae) * 128 + q * 4;
  const float* frow = f + (size_t)ae * 128 + q * 4;

  // A chunk buffers: [buf][128 rows][40 f16] (80 B stride)
  auto abuf = [&](int b) -> f16_t* { return (f16_t*)(smem + b * 10240); };

  auto gldA = [&](int c) -> float4 {  // c < 8 only
    return (c < 4) ? *(const float4*)(hrow + c * 32)
                   : *(const float4*)(frow + (c - 4) * 32);
  };
  auto dswA = [&](int c, float4 v) {
    if (c >= 8) {
      const int cb = (c - 8) * 32 + q * 4;
#pragma unroll
      for (int j = 0; j < 4; ++j) {
        int cc = cb + j;
        ((float*)&v)[j] =
            (cc < 100) ? __cosf(dtv * exp2f(TIMEW_LOG2 * (float)cc)) : 0.f;
      }
    }
    f16x4 w;
    w[0] = (f16_t)v.x; w[1] = (f16_t)v.y; w[2] = (f16_t)v.z; w[3] = (f16_t)v.w;
    *(f16x4*)&abuf(c & 1)[row * 40 + q * 4] = w;
  };
  auto gldB = [&](int c, f16x8* dstB) {
    const f16_t* bb = weffp + (size_t)c * 16384 + g * 4096 + (wn * 64 + m16) * 8;
#pragma unroll
    for (int n = 0; n < 4; ++n) dstB[n] = *(const f16x8*)(bb + n * 128);
  };

  f32x4 acc[4][4];
#pragma unroll
  for (int mt = 0; mt < 4; ++mt)
#pragma unroll
    for (int n = 0; n < 4; ++n) acc[mt][n] = zero4();

  float4 aR[2];
  f16x8 bb[2][4];

  // prologue: chunks 0,1 loaded; chunk0 staged; chunk2 load in flight; B(0)
  aR[0] = gldA(0);
  aR[1] = gldA(1);
  gldB(0, bb[0]);
  dswA(0, aR[0]);
  aR[0] = gldA(2);
  BARRIER();

#pragma unroll
  for (int kc = 0; kc < 12; ++kc) {
    // stage next chunk's A into the other LDS buffer
    if (kc < 11) dswA(kc + 1, aR[(kc + 1) & 1]);
    // issue A global load 3 chunks ahead (only chunks < 8 come from memory)
    if (kc + 3 < 8) aR[(kc + 3) & 1] = gldA(kc + 3);
    // B prefetch one chunk ahead (L2-resident)
    if (kc < 11) gldB(kc + 1, bb[(kc + 1) & 1]);

    // MFMA on current chunk
    const f16_t* Ac = abuf(kc & 1);
#pragma unroll
    for (int mt = 0; mt < 4; ++mt) {
      const int r2 = wm * 64 + mt * 16 + m16;
      f16x8 afr = *(const f16x8*)&Ac[r2 * 40 + g * 8];
#pragma unroll
      for (int n = 0; n < 4; ++n)
        acc[mt][n] = MFMA16(afr, bb[kc & 1][n], acc[mt][n]);
    }

    BARRIER();
  }

  // ---- epilogue (smem A bufs dead; ep = [128][264] f16 = 66 KB)
  f16_t* ep = (f16_t*)smem;

  // pass 0: stage Kh (cols 0..255), compute att; Kh never stored to global
  if ((wn >> 2) == 0) {
#pragma unroll
    for (int n = 0; n < 4; ++n) {
      const int c256 = (wn & 3) * 64 + n * 16 + m16;
      const float bias = beff[c256];
#pragma unroll
      for (int mt = 0; mt < 4; ++mt)
#pragma unroll
        for (int j = 0; j < 4; ++j) {
          const int r2 = wm * 64 + mt * 16 + (g << 2) + j;
          ep[r2 * 264 + c256] = (f16_t)(acc[mt][n][j] + bias);
        }
    }
  }
  BARRIER();

  {
    const int r2 = tid >> 3;              // 0..127
    const int hp = (tid & 7);             // head 0..7
    const int e = ebase + r2;
    if (e < E) {
      const int de = dst[e];
      const float* qp = qhd + (size_t)de * 256 + hp * 32;
      const f16_t* kp = ep + r2 * 264 + hp * 32;
      float s = 0.f;
#pragma unroll
      for (int jj = 0; jj < 32; jj += 4) {
        float4 qv = *(const float4*)(qp + jj);
        f16x4 kv = *(const f16x4*)(kp + jj);
        s += qv.x * (float)kv[0] + qv.y * (float)kv[1] +
             qv.z * (float)kv[2] + qv.w * (float)kv[3];
      }
      s = (s > 0.f) ? s : 0.2f * s;
      att[(size_t)e * 8 + hp] = __expf(s);
    }
  }
  BARRIER();  // att LDS reads done before Vh staging overwrites ep

  // pass 1: stage Vh (cols 256..511), coalesced store
  if ((wn >> 2) == 1) {
#pragma unroll
    for (int n = 0; n < 4; ++n) {
      const int c256 = (wn & 3) * 64 + n * 16 + m16;
      const float bias = beff[256 + c256];
#pragma unroll
      for (int mt = 0; mt < 4; ++mt)
#pragma unroll
        for (int j = 0; j < 4; ++j) {
          const int r2 = wm * 64 + mt * 16 + (g << 2) + j;
          ep[r2 * 264 + c256] = (f16_t)(acc[mt][n][j] + bias);
        }
    }
  }
  BARRIER();

#pragma unroll
  for (int sweep = 0; sweep < 4; ++sweep) {
    const int flat = sweep * 8192 + tid * 8;
    const int r2 = flat >> 8, cc = flat & 255;
    const int e = ebase + r2;
    if (e < E) {
      f16x8 v = *(const f16x8*)&ep[r2 * 264 + cc];
      *(f16x8*)&vhg[(size_t)e * 256 + cc] = v;
    }
  }
}

// ---------------------------------------------------------------------------
// k_agg: one wave per dst node (csr gather of att + V). No-max softmax.
// ---------------------------------------------------------------------------
__global__ __launch_bounds__(256) void k_agg(
    const float* __restrict__ qhd, const f16_t* __restrict__ khs,
    const f16_t* __restrict__ vhs, const float* __restrict__ att,
    const f16_t* __restrict__ vhg, const int* __restrict__ rs,
    const int* __restrict__ csr, const float* __restrict__ lng,
    const float* __restrict__ lnb, float* __restrict__ out, int D) {
  const int lane = threadIdx.x & 63;
  const int d = blockIdx.x * 4 + (threadIdx.x >> 6);
  if (d >= D) return;
  const int c0 = lane * 4;
  const int hd = lane >> 3;

  // self-loop term (score from f32 Q and f16 K_self)
  float den, a0, a1, a2, a3;
  {
    float4 qv = *(const float4*)(qhd + (size_t)d * 256 + c0);
    f16x4 ku = *(const f16x4*)(khs + (size_t)d * 256 + c0);
    f16x4 vu = *(const f16x4*)(vhs + (size_t)d * 256 + c0);
    float s = qv.x * (float)ku[0] + qv.y * (float)ku[1] +
              qv.z * (float)ku[2] + qv.w * (float)ku[3];
    s += __shfl_xor(s, 1); s += __shfl_xor(s, 2); s += __shfl_xor(s, 4);
    s = (s > 0.f) ? s : 0.2f * s;
    float ee = __expf(s);
    den = ee;
    a0 = ee * (float)vu[0]; a1 = ee * (float)vu[1];
    a2 = ee * (float)vu[2]; a3 = ee * (float)vu[3];
  }

  const int beg = rs[d], end = rs[d + 1];
  f16x4 vN;
  float eN;
  if (beg < end) {
    int e = csr[beg];
    eN = att[(size_t)e * 8 + hd];
    vN = *(const f16x4*)(vhg + (size_t)e * 256 + c0);
  }
  for (int idx = beg; idx < end; ++idx) {
    f16x4 vu = vN;
    float ee = eN;
    if (idx + 1 < end) {  // 1-deep prefetch
      int e = csr[idx + 1];
      eN = att[(size_t)e * 8 + hd];
      vN = *(const f16x4*)(vhg + (size_t)e * 256 + c0);
    }
    den += ee;
    a0 = fmaf(ee, (float)vu[0], a0); a1 = fmaf(ee, (float)vu[1], a1);
    a2 = fmaf(ee, (float)vu[2], a2); a3 = fmaf(ee, (float)vu[3], a3);
  }

  float x0 = fmaxf(a0 / den, 0.f), x1 = fmaxf(a1 / den, 0.f);
  float x2 = fmaxf(a2 / den, 0.f), x3 = fmaxf(a3 / den, 0.f);

  float s1 = x0 + x1 + x2 + x3;
#pragma unroll
  for (int m = 1; m < 64; m <<= 1) s1 += __shfl_xor(s1, m);
  float mu = s1 * (1.f / 256.f);
  float d0 = x0 - mu, d1 = x1 - mu, d2 = x2 - mu, d3 = x3 - mu;
  float s2 = d0 * d0 + d1 * d1 + d2 * d2 + d3 * d3;
#pragma unroll
  for (int m = 1; m < 64; m <<= 1) s2 += __shfl_xor(s2, m);
  float rstd = rsqrtf(s2 * (1.f / 256.f) + 1e-5f);

  float4 gg = *(const float4*)(lng + c0);
  float4 bb = *(const float4*)(lnb + c0);
  float4 o;
  o.x = d0 * rstd * gg.x + bb.x;
  o.y = d1 * rstd * gg.y + bb.y;
  o.z = d2 * rstd * gg.z + bb.z;
  o.w = d3 * rstd * gg.w + bb.w;
  *(float4*)(out + (size_t)d * 256 + c0) = o;
}

// ---------------------------------------------------------------------------
extern "C" void kernel_launch(void* const* d_in, const int* in_sizes, int n_in,
                              void* d_out, int out_size, void* d_ws,
                              size_t ws_size, hipStream_t stream) {
  const float* h       = (const float*)d_in[0];
  const float* f       = (const float*)d_in[1];
  const float* dt      = (const float*)d_in[2];
  const float* wq_lin  = (const float*)d_in[3];
  const float* bq_lin  = (const float*)d_in[4];
  const float* wkv_lin = (const float*)d_in[5];
  const float* bkv_lin = (const float*)d_in[6];
  const float* wq      = (const float*)d_in[7];
  const float* bq      = (const float*)d_in[8];
  const float* wk      = (const float*)d_in[9];
  const float* bk      = (const float*)d_in[10];
  const float* wv      = (const float*)d_in[11];
  const float* bv      = (const float*)d_in[12];
  const float* lng     = (const float*)d_in[13];
  const float* lnb     = (const float*)d_in[14];
  const int*   dst     = (const int*)d_in[15];

  const int S = in_sizes[0] / 128;
  const int E = in_sizes[2];
  const int D = S - E;
  float* out = (float*)d_out;

  char* p = (char*)d_ws;
  size_t off = 0;
  auto take = [&](size_t bytes) -> char* {
    char* r = p + off;
    off += (bytes + 255) & ~(size_t)255;
    return r;
  };
  f16_t* wq1   = (f16_t*)take((size_t)32768 * 2);
  f16_t* w3    = (f16_t*)take((size_t)196608 * 2);
  float* bqe   = (float*)take((size_t)256 * 4);
  f16_t* weffp = (f16_t*)take((size_t)196608 * 2);
  float* beff  = (float*)take((size_t)512 * 4);
  float* qhd   = (float*)take((size_t)D * 256 * 4);
  f16_t* khs   = (f16_t*)take((size_t)D * 256 * 2);
  f16_t* vhs   = (f16_t*)take((size_t)D * 256 * 2);
  float* att   = (float*)take((size_t)E * 8 * 4);
  f16_t* vhg   = (f16_t*)take((size_t)E * 256 * 2);
  int*   rs    = (int*)  take((size_t)(D + 1) * 4);
  int*   cur   = (int*)  take((size_t)D * 4);
  int*   csr   = (int*)  take((size_t)E * 4);

  if (off > ws_size) {
    k_sentinel<<<(out_size + 255) / 256, 256, 0, stream>>>(out, out_size);
    return;
  }

  hipMemsetAsync(rs, 0, (size_t)(D + 1) * 4, stream);
  k_prep<<<898, 256, 0, stream>>>(wq_lin, bq_lin, wq, wk, wv, wq1, w3, bqe);
  k_wcomp<<<512, 384, 0, stream>>>(wkv_lin, bkv_lin, wk, bk, wv, bv, weffp,
                                   beff);
  k_hist<<<(E + 255) / 256, 256, 0, stream>>>(dst, rs, E);
  k_scan<<<1, 1024, 0, stream>>>(rs, cur, D);
  k_scatter<<<(E + 255) / 256, 256, 0, stream>>>(dst, cur, csr, E);
  k_q<<<(D + 63) / 64, 512, 0, stream>>>(h, bqe, bq, bk, bv, wq1, w3, qhd, khs,
                                         vhs, D);
  k_kv<<<(E + 127) / 128, 1024, 0, stream>>>(h, f, dt, weffp, beff, dst, qhd,
                                             att, vhg, D, E);
  k_agg<<<(D + 3) / 4, 256, 0, stream>>>(qhd, khs, vhs, att, vhg, rs, csr, lng,
                                         lnb, out, D);
}

// Round 10
// 697.385 us; speedup vs baseline: 1.8099x; 1.0483x over previous
//
#include <hip/hip_runtime.h>
#include <cstdint>
#include <cstddef>

// ---------------------------------------------------------------------------
// TGN transformer attention layer, MI355X (gfx950).
//   k_prep  : pack k_q weights to f16; bq_eff (time-ones folded)
//   k_wcomp : Weff = [Wk;Wv] @ Wkv (f32) -> f16 fragment-packed; beff
//   CSR     : hist/scan/scatter over dst (scatter also emits dstc[pos])
//   k_q     : D rows: Q_ori -> Qh(f32), Kh_self, Vh_self (f16)
//   k_kv    : GEMM C[pos x 512] = X[csr[pos]] @ Weff^T + beff, CSR-ordered.
//             BK=128 super-chunks: A staged per-super in LDS (2 buffers),
//             only 3 K-loop barriers/tile; B VGPR-dbuf per 32-k sub-chunk.
//             Epilogue: Kh->LDS -> att[pos][h]=exp(leaky(Q[dstc[pos]].Kh))
//             (run-coherent Q gather); Vh -> vhg[pos] sequential stores.
//   k_agg   : per-dst wave: STREAMS att+V rows [rs[d],rs[d+1]) + self term,
//             weighted sum + relu + LN
// ---------------------------------------------------------------------------

typedef _Float16 f16_t;
typedef _Float16 f16x8 __attribute__((ext_vector_type(8)));
typedef _Float16 f16x4 __attribute__((ext_vector_type(4)));
typedef float    f32x4 __attribute__((ext_vector_type(4)));

#define MFMA16(a, b, c) __builtin_amdgcn_mfma_f32_16x16x32_f16(a, b, c, 0, 0, 0)

#define BARRIER()                                         \
  do {                                                    \
    asm volatile("s_waitcnt lgkmcnt(0)" ::: "memory");    \
    __builtin_amdgcn_sched_barrier(0);                    \
    __builtin_amdgcn_s_barrier();                         \
    __builtin_amdgcn_sched_barrier(0);                    \
  } while (0)

static __device__ __forceinline__ f32x4 zero4() {
  f32x4 v; v[0] = 0.f; v[1] = 0.f; v[2] = 0.f; v[3] = 0.f; return v;
}

// w_j = 10^(-9 j / 99)  ->  exp2(j * (-9*log2(10)/99))
#define TIMEW_LOG2 (-0.30199346317157837f)

// ---------------------------------------------------------------------------
__global__ void k_prep(const float* __restrict__ wq_lin,
                       const float* __restrict__ bq_lin,
                       const float* __restrict__ wq,
                       const float* __restrict__ wk,
                       const float* __restrict__ wv,
                       f16_t* __restrict__ wq1,
                       f16_t* __restrict__ w3,
                       float* __restrict__ bqe) {
  int i = blockIdx.x * 256 + threadIdx.x;
  if (i < 32768) {
    int o = i >> 7, k = i & 127;
    wq1[i] = (f16_t)wq_lin[o * 228 + k];
  } else if (i < 229376) {
    int j = i - 32768;
    int r = j >> 8, k = j & 255;
    const float* src = (r < 256) ? wq : ((r < 512) ? wk : wv);
    w3[j] = (f16_t)src[(r & 255) * 256 + k];
  } else if (i < 229632) {
    int o = i - 229376;
    float s = bq_lin[o];
    for (int j = 0; j < 100; ++j) s += wq_lin[o * 228 + 128 + j];
    bqe[o] = s;
  }
}

// ---------------------------------------------------------------------------
// k_wcomp: Weff[oc][c] = sum_m W23[oc][m] * Wkv[m][c]; packed:
//   idx = kc*16384 + g*4096 + oc*8 + j   (c = kc*32 + g*8 + j)
// ---------------------------------------------------------------------------
__global__ __launch_bounds__(384) void k_wcomp(
    const float* __restrict__ wkv_lin, const float* __restrict__ bkv,
    const float* __restrict__ wk, const float* __restrict__ bk,
    const float* __restrict__ wv, const float* __restrict__ bv,
    f16_t* __restrict__ weffp, float* __restrict__ beff) {
  __shared__ float wrow[256];
  const int oc = blockIdx.x;
  const float* src = (oc < 256) ? (wk + (size_t)oc * 256)
                                : (wv + (size_t)(oc - 256) * 256);
  const int t = threadIdx.x;
  if (t < 256) wrow[t] = src[t];
  __syncthreads();

  float acc = 0.f;
  if (t < 356) {
#pragma unroll 4
    for (int m = 0; m < 256; ++m) acc += wrow[m] * wkv_lin[(size_t)m * 356 + t];
  }
  int kc = t >> 5, g = (t >> 3) & 3, j = t & 7;
  weffp[(size_t)kc * 16384 + g * 4096 + oc * 8 + j] = (f16_t)acc;

  if (t == 0) {
    float b = (oc < 256) ? bk[oc] : bv[oc - 256];
    for (int m = 0; m < 256; ++m) b += wrow[m] * bkv[m];
    beff[oc] = b;
  }
}

// ---------------------------------------------------------------------------
// CSR build
// ---------------------------------------------------------------------------
__global__ void k_hist(const int* __restrict__ dst, int* __restrict__ rs, int E) {
  int e = blockIdx.x * 256 + threadIdx.x;
  if (e < E) atomicAdd(&rs[dst[e] + 1], 1);
}

__global__ void k_scan(int* __restrict__ rs, int* __restrict__ cur, int D) {
  __shared__ int sd[1024];
  __shared__ int srun;
  const int t = threadIdx.x;
  if (t == 0) srun = 0;
  __syncthreads();
  for (int base = 0; base < D; base += 1024) {
    const int i = base + t;
    int c = (i < D) ? rs[i + 1] : 0;
    sd[t] = c;
    __syncthreads();
    for (int off = 1; off < 1024; off <<= 1) {
      int v = (t >= off) ? sd[t - off] : 0;
      __syncthreads();
      sd[t] += v;
      __syncthreads();
    }
    const int incl = sd[t];
    const int run = srun;
    __syncthreads();
    if (i < D) {
      cur[i] = run + incl - c;
      rs[i + 1] = run + incl;
    }
    if (t == 1023) srun = run + sd[1023];
    __syncthreads();
  }
}

__global__ void k_scatter(const int* __restrict__ dst, int* __restrict__ cur,
                          int* __restrict__ csr, int* __restrict__ dstc, int E) {
  int e = blockIdx.x * 256 + threadIdx.x;
  if (e < E) {
    int d = dst[e];
    int pos = atomicAdd(&cur[d], 1);
    csr[pos] = e;
    dstc[pos] = d;
  }
}

__global__ void k_sentinel(float* __restrict__ o, int n) {
  int i = blockIdx.x * 256 + threadIdx.x;
  if (i < n) o[i] = 1e30f;
}

// ---------------------------------------------------------------------------
// k_q: 64 dst rows per block, 8 waves (small kernel, D=25k rows).
// ---------------------------------------------------------------------------
__global__ __launch_bounds__(512) void k_q(
    const float* __restrict__ h, const float* __restrict__ bqe,
    const float* __restrict__ bq, const float* __restrict__ bk,
    const float* __restrict__ bv, const f16_t* __restrict__ wq1,
    const f16_t* __restrict__ w3, float* __restrict__ qhd,
    f16_t* __restrict__ khs, f16_t* __restrict__ vhs, int D) {
  __shared__ f16_t sm[64 * 256];
  f16_t* xs = sm;
  f16_t* ks = sm;
  const int tid = threadIdx.x;
  const int dbase = blockIdx.x * 64;

  {
    const int r = tid >> 3, q = tid & 7;
    const int dd = min(dbase + r, D - 1);
    const int sw = r & 7;
    const float* p = h + (size_t)dd * 128 + q * 16;
#pragma unroll
    for (int u = 0; u < 2; ++u) {
      float4 v0 = *(const float4*)(p + u * 8);
      float4 v1 = *(const float4*)(p + u * 8 + 4);
      f16x8 w8;
      w8[0] = (f16_t)v0.x; w8[1] = (f16_t)v0.y; w8[2] = (f16_t)v0.z; w8[3] = (f16_t)v0.w;
      w8[4] = (f16_t)v1.x; w8[5] = (f16_t)v1.y; w8[6] = (f16_t)v1.z; w8[7] = (f16_t)v1.w;
      *(f16x8*)&xs[r * 128 + (((2 * q + u) ^ sw) << 3)] = w8;
    }
  }
  __syncthreads();

  const int lane = tid & 63;
  const int wv_ = tid >> 6;
  const int m16 = lane & 15;
  const int g = lane >> 4;

  f32x4 acc1[4][2];
#pragma unroll
  for (int mt = 0; mt < 4; ++mt)
#pragma unroll
    for (int nt = 0; nt < 2; ++nt) acc1[mt][nt] = zero4();

#pragma unroll
  for (int kt = 0; kt < 4; ++kt) {
    f16x8 a[4];
#pragma unroll
    for (int mt = 0; mt < 4; ++mt) {
      int row = mt * 16 + m16;
      a[mt] = *(const f16x8*)&xs[row * 128 + ((((kt << 2) + g) ^ (row & 7)) << 3)];
    }
#pragma unroll
    for (int nt = 0; nt < 2; ++nt) {
      int col = wv_ * 32 + nt * 16 + m16;
      f16x8 b = *(const f16x8*)&wq1[(size_t)col * 128 + (kt << 5) + (g << 3)];
#pragma unroll
      for (int mt = 0; mt < 4; ++mt) acc1[mt][nt] = MFMA16(a[mt], b, acc1[mt][nt]);
    }
  }
  __syncthreads();

#pragma unroll
  for (int nt = 0; nt < 2; ++nt) {
    int col = wv_ * 32 + nt * 16 + m16;
    float bias = bqe[col];
#pragma unroll
    for (int mt = 0; mt < 4; ++mt)
#pragma unroll
      for (int j = 0; j < 4; ++j) {
        int row = mt * 16 + (g << 2) + j;
        ks[row * 256 + ((((col >> 3) ^ (row & 7)) << 3)) + (col & 7)] =
            (f16_t)(acc1[mt][nt][j] + bias);
      }
  }
  __syncthreads();

#pragma unroll
  for (int p = 0; p < 3; ++p) {
    const f16_t* wsec = w3 + ((size_t)p << 16);
    const float* bsec = (p == 0) ? bq : ((p == 1) ? bk : bv);
    f32x4 acc[4][2];
#pragma unroll
    for (int mt = 0; mt < 4; ++mt)
#pragma unroll
      for (int nt = 0; nt < 2; ++nt) acc[mt][nt] = zero4();
#pragma unroll
    for (int kt = 0; kt < 8; ++kt) {
      f16x8 a[4];
#pragma unroll
      for (int mt = 0; mt < 4; ++mt) {
        int row = mt * 16 + m16;
        a[mt] = *(const f16x8*)&ks[row * 256 + ((((kt << 2) + g) ^ (row & 7)) << 3)];
      }
#pragma unroll
      for (int nt = 0; nt < 2; ++nt) {
        int col = wv_ * 32 + nt * 16 + m16;
        f16x8 b = *(const f16x8*)&wsec[(size_t)col * 256 + (kt << 5) + (g << 3)];
#pragma unroll
        for (int mt = 0; mt < 4; ++mt) acc[mt][nt] = MFMA16(a[mt], b, acc[mt][nt]);
      }
    }
#pragma unroll
    for (int nt = 0; nt < 2; ++nt) {
      int col = wv_ * 32 + nt * 16 + m16;
      float bias = bsec[col];
#pragma unroll
      for (int mt = 0; mt < 4; ++mt)
#pragma unroll
        for (int j = 0; j < 4; ++j) {
          int row = mt * 16 + (g << 2) + j;
          int dd = dbase + row;
          if (dd < D) {
            float val = acc[mt][nt][j] + bias;
            if (p == 0)
              qhd[(size_t)dd * 256 + col] = val;
            else if (p == 1)
              khs[(size_t)dd * 256 + col] = (f16_t)val;
            else
              vhs[(size_t)dd * 256 + col] = (f16_t)val;
          }
        }
    }
  }
}

// ---------------------------------------------------------------------------
// k_kv: CSR-ordered GEMM + att fusion.
//   1024 threads = 16 waves (wm 2 x wn 8, 64x64/wave), tile = 128 CSR rows.
//   K split into 3 supers of 128 (h | f | time); A staged per-super in LDS
//   (2 x 40 KB buffers, stride-80B rows); B (weffp, L2) VGPR-dbuf per 32-k
//   sub-chunk.  3 K-loop barriers + 4 epilogue barriers per tile.
// ---------------------------------------------------------------------------
__global__ __launch_bounds__(1024, 2) void k_kv(
    const float* __restrict__ h, const float* __restrict__ f,
    const float* __restrict__ dt, const f16_t* __restrict__ weffp,
    const float* __restrict__ beff, const int* __restrict__ csr,
    const int* __restrict__ dstc, const float* __restrict__ qhd,
    float* __restrict__ att, f16_t* __restrict__ vhg, int D, int E) {
  __shared__ __align__(16) unsigned char smem[81920];  // 2 x 40 KB A supers

  const int tid = threadIdx.x;
  const int pbase = blockIdx.x * 128;
  const int row = tid >> 3, q = tid & 7;
  const int lane = tid & 63, wid = tid >> 6;
  const int wm = wid >> 3, wn = wid & 7;
  const int m16 = lane & 15, g = lane >> 4;

  const int pclamp = min(pbase + row, E - 1);
  const int ec = csr[pclamp];
  const float dtv = dt[ec];
  const float* hrow = h + (size_t)(D + ec) * 128 + q * 4;
  const float* frow = f + (size_t)ec * 128 + q * 4;

  auto stageA = [&](int buf, int sub, float4 v) {
    f16x4 w;
    w[0] = (f16_t)v.x; w[1] = (f16_t)v.y; w[2] = (f16_t)v.z; w[3] = (f16_t)v.w;
    *(f16x4*)(smem + buf * 40960 + sub * 10240 + row * 80 + q * 8) = w;
  };
  const f16_t* wb = weffp + (size_t)g * 4096 + ((size_t)(wn * 64 + m16) << 3);
  auto gldB = [&](int kc, f16x8* d) {
    const f16_t* pB = wb + (size_t)kc * 16384;
#pragma unroll
    for (int n = 0; n < 4; ++n) d[n] = *(const f16x8*)(pB + n * 128);
  };

  f32x4 acc[4][4];
#pragma unroll
  for (int mt = 0; mt < 4; ++mt)
#pragma unroll
    for (int n = 0; n < 4; ++n) acc[mt][n] = zero4();

  auto doChunk = [&](int kc, const f16x8* bbuf) {
    const unsigned char* Ac =
        smem + (((kc >> 2) == 1) ? 40960 : 0) + (kc & 3) * 10240;
#pragma unroll
    for (int mt = 0; mt < 4; ++mt) {
      f16x8 afr = *(const f16x8*)(Ac + (wm * 64 + mt * 16 + m16) * 80 + g * 16);
#pragma unroll
      for (int n = 0; n < 4; ++n) acc[mt][n] = MFMA16(afr, bbuf[n], acc[mt][n]);
    }
  };

  // load h-super + f-super (gathered 512B rows); stage h into buf0
  float4 hv[4], fv[4];
#pragma unroll
  for (int s = 0; s < 4; ++s) hv[s] = *(const float4*)(hrow + s * 32);
#pragma unroll
  for (int s = 0; s < 4; ++s) fv[s] = *(const float4*)(frow + s * 32);
#pragma unroll
  for (int s = 0; s < 4; ++s) stageA(0, s, hv[s]);
  BARRIER();  // A: buf0 (h) ready

  f16x8 bb0[4], bb1[4];
  gldB(0, bb0);
  // stage f-super into buf1 (consumed after barrier B)
#pragma unroll
  for (int s = 0; s < 4; ++s) stageA(1, s, fv[s]);

  gldB(1, bb1); doChunk(0, bb0);
  gldB(2, bb0); doChunk(1, bb1);
  gldB(3, bb1); doChunk(2, bb0);
  gldB(4, bb0); doChunk(3, bb1);
  BARRIER();  // B: buf1 (f) ready, buf0 free

  // stage time-super into buf0 (consumed after barrier C)
#pragma unroll
  for (int s = 0; s < 4; ++s) {
    float4 a;
#pragma unroll
    for (int j = 0; j < 4; ++j) {
      int cc = s * 32 + q * 4 + j;
      ((float*)&a)[j] =
          (cc < 100) ? __cosf(dtv * exp2f(TIMEW_LOG2 * (float)cc)) : 0.f;
    }
    stageA(0, s, a);
  }
  gldB(5, bb1); doChunk(4, bb0);
  gldB(6, bb0); doChunk(5, bb1);
  gldB(7, bb1); doChunk(6, bb0);
  gldB(8, bb0); doChunk(7, bb1);
  BARRIER();  // C: buf0 (time) ready

  gldB(9, bb1);  doChunk(8, bb0);
  gldB(10, bb0); doChunk(9, bb1);
  gldB(11, bb1); doChunk(10, bb0);
  doChunk(11, bb1);
  BARRIER();  // D: K done, both bufs dead

  // ---- epilogue: ep = [128][264] f16 (67584 B, fits in smem)
  f16_t* ep = (f16_t*)smem;

  // pass 0: Kh (cols 0..255) -> LDS
  if ((wn >> 2) == 0) {
#pragma unroll
    for (int n = 0; n < 4; ++n) {
      const int c256 = (wn & 3) * 64 + n * 16 + m16;
      const float bias = beff[c256];
#pragma unroll
      for (int mt = 0; mt < 4; ++mt)
#pragma unroll
        for (int j = 0; j < 4; ++j) {
          const int r2 = wm * 64 + mt * 16 + (g << 2) + j;
          ep[r2 * 264 + c256] = (f16_t)(acc[mt][n][j] + bias);
        }
    }
  }
  BARRIER();  // E

  // att: run-coherent Q gather (CSR order -> ~20 consecutive rows same dst)
  {
    const int r2 = tid >> 3, hp = tid & 7;
    const int p2 = pbase + r2;
    if (p2 < E) {
      const int de = dstc[p2];
      const float* qp = qhd + (size_t)de * 256 + hp * 32;
      const f16_t* kp = ep + r2 * 264 + hp * 32;
      float s = 0.f;
#pragma unroll
      for (int jj = 0; jj < 32; jj += 4) {
        float4 qv = *(const float4*)(qp + jj);
        f16x4 kv = *(const f16x4*)(kp + jj);
        s += qv.x * (float)kv[0] + qv.y * (float)kv[1] +
             qv.z * (float)kv[2] + qv.w * (float)kv[3];
      }
      s = (s > 0.f) ? s : 0.2f * s;
      att[(size_t)p2 * 8 + hp] = __expf(s);
    }
  }
  BARRIER();  // F: Kh reads done before Vh staging overwrites ep

  // pass 1: Vh (cols 256..511) -> LDS
  if ((wn >> 2) == 1) {
#pragma unroll
    for (int n = 0; n < 4; ++n) {
      const int c256 = (wn & 3) * 64 + n * 16 + m16;
      const float bias = beff[256 + c256];
#pragma unroll
      for (int mt = 0; mt < 4; ++mt)
#pragma unroll
        for (int j = 0; j < 4; ++j) {
          const int r2 = wm * 64 + mt * 16 + (g << 2) + j;
          ep[r2 * 264 + c256] = (f16_t)(acc[mt][n][j] + bias);
        }
    }
  }
  BARRIER();  // G

  // Vh stores: CSR-position rows -> fully sequential, coalesced
#pragma unroll
  for (int sweep = 0; sweep < 4; ++sweep) {
    const int flat = sweep * 8192 + tid * 8;
    const int r2 = flat >> 8, cc = flat & 255;
    const int p2 = pbase + r2;
    if (p2 < E) {
      f16x8 v = *(const f16x8*)&ep[r2 * 264 + cc];
      *(f16x8*)&vhg[(size_t)p2 * 256 + cc] = v;
    }
  }
}

// ---------------------------------------------------------------------------
// k_agg: one wave per dst node; att + V rows are CSR-ordered -> streaming.
// ---------------------------------------------------------------------------
__global__ __launch_bounds__(256) void k_agg(
    const float* __restrict__ qhd, const f16_t* __restrict__ khs,
    const f16_t* __restrict__ vhs, const float* __restrict__ att,
    const f16_t* __restrict__ vhg, const int* __restrict__ rs,
    const float* __restrict__ lng, const float* __restrict__ lnb,
    float* __restrict__ out, int D) {
  const int lane = threadIdx.x & 63;
  const int d = blockIdx.x * 4 + (threadIdx.x >> 6);
  if (d >= D) return;
  const int c0 = lane * 4;
  const int hd = lane >> 3;

  // self-loop term (score from f32 Q and f16 K_self)
  float den, a0, a1, a2, a3;
  {
    float4 qv = *(const float4*)(qhd + (size_t)d * 256 + c0);
    f16x4 ku = *(const f16x4*)(khs + (size_t)d * 256 + c0);
    f16x4 vu = *(const f16x4*)(vhs + (size_t)d * 256 + c0);
    float s = qv.x * (float)ku[0] + qv.y * (float)ku[1] +
              qv.z * (float)ku[2] + qv.w * (float)ku[3];
    s += __shfl_xor(s, 1); s += __shfl_xor(s, 2); s += __shfl_xor(s, 4);
    s = (s > 0.f) ? s : 0.2f * s;
    float ee = __expf(s);
    den = ee;
    a0 = ee * (float)vu[0]; a1 = ee * (float)vu[1];
    a2 = ee * (float)vu[2]; a3 = ee * (float)vu[3];
  }

  const int beg = rs[d], end = rs[d + 1];
  f16x4 vN;
  float eN;
  if (beg < end) {
    eN = att[(size_t)beg * 8 + hd];
    vN = *(const f16x4*)(vhg + (size_t)beg * 256 + c0);
  }
  for (int idx = beg; idx < end; ++idx) {
    f16x4 vu = vN;
    float ee = eN;
    if (idx + 1 < end) {  // 1-deep prefetch (sequential rows)
      eN = att[(size_t)(idx + 1) * 8 + hd];
      vN = *(const f16x4*)(vhg + (size_t)(idx + 1) * 256 + c0);
    }
    den += ee;
    a0 = fmaf(ee, (float)vu[0], a0); a1 = fmaf(ee, (float)vu[1], a1);
    a2 = fmaf(ee, (float)vu[2], a2); a3 = fmaf(ee, (float)vu[3], a3);
  }

  float x0 = fmaxf(a0 / den, 0.f), x1 = fmaxf(a1 / den, 0.f);
  float x2 = fmaxf(a2 / den, 0.f), x3 = fmaxf(a3 / den, 0.f);

  float s1 = x0 + x1 + x2 + x3;
#pragma unroll
  for (int m = 1; m < 64; m <<= 1) s1 += __shfl_xor(s1, m);
  float mu = s1 * (1.f / 256.f);
  float d0 = x0 - mu, d1 = x1 - mu, d2 = x2 - mu, d3 = x3 - mu;
  float s2 = d0 * d0 + d1 * d1 + d2 * d2 + d3 * d3;
#pragma unroll
  for (int m = 1; m < 64; m <<= 1) s2 += __shfl_xor(s2, m);
  float rstd = rsqrtf(s2 * (1.f / 256.f) + 1e-5f);

  float4 gg = *(const float4*)(lng + c0);
  float4 bb = *(const float4*)(lnb + c0);
  float4 o;
  o.x = d0 * rstd * gg.x + bb.x;
  o.y = d1 * rstd * gg.y + bb.y;
  o.z = d2 * rstd * gg.z + bb.z;
  o.w = d3 * rstd * gg.w + bb.w;
  *(float4*)(out + (size_t)d * 256 + c0) = o;
}

// ---------------------------------------------------------------------------
extern "C" void kernel_launch(void* const* d_in, const int* in_sizes, int n_in,
                              void* d_out, int out_size, void* d_ws,
                              size_t ws_size, hipStream_t stream) {
  const float* h       = (const float*)d_in[0];
  const float* f       = (const float*)d_in[1];
  const float* dt      = (const float*)d_in[2];
  const float* wq_lin  = (const float*)d_in[3];
  const float* bq_lin  = (const float*)d_in[4];
  const float* wkv_lin = (const float*)d_in[5];
  const float* bkv_lin = (const float*)d_in[6];
  const float* wq      = (const float*)d_in[7];
  const float* bq      = (const float*)d_in[8];
  const float* wk      = (const float*)d_in[9];
  const float* bk      = (const float*)d_in[10];
  const float* wv      = (const float*)d_in[11];
  const float* bv      = (const float*)d_in[12];
  const float* lng     = (const float*)d_in[13];
  const float* lnb     = (const float*)d_in[14];
  const int*   dst     = (const int*)d_in[15];

  const int S = in_sizes[0] / 128;
  const int E = in_sizes[2];
  const int D = S - E;
  float* out = (float*)d_out;

  char* p = (char*)d_ws;
  size_t off = 0;
  auto take = [&](size_t bytes) -> char* {
    char* r = p + off;
    off += (bytes + 255) & ~(size_t)255;
    return r;
  };
  f16_t* wq1   = (f16_t*)take((size_t)32768 * 2);
  f16_t* w3    = (f16_t*)take((size_t)196608 * 2);
  float* bqe   = (float*)take((size_t)256 * 4);
  f16_t* weffp = (f16_t*)take((size_t)196608 * 2);
  float* beff  = (float*)take((size_t)512 * 4);
  float* qhd   = (float*)take((size_t)D * 256 * 4);
  f16_t* khs   = (f16_t*)take((size_t)D * 256 * 2);
  f16_t* vhs   = (f16_t*)take((size_t)D * 256 * 2);
  float* att   = (float*)take((size_t)E * 8 * 4);
  f16_t* vhg   = (f16_t*)take((size_t)E * 256 * 2);
  int*   rs    = (int*)  take((size_t)(D + 1) * 4);
  int*   cur   = (int*)  take((size_t)D * 4);
  int*   csr   = (int*)  take((size_t)E * 4);
  int*   dstc  = (int*)  take((size_t)E * 4);

  if (off > ws_size) {
    k_sentinel<<<(out_size + 255) / 256, 256, 0, stream>>>(out, out_size);
    return;
  }

  hipMemsetAsync(rs, 0, (size_t)(D + 1) * 4, stream);
  k_prep<<<898, 256, 0, stream>>>(wq_lin, bq_lin, wq, wk, wv, wq1, w3, bqe);
  k_wcomp<<<512, 384, 0, stream>>>(wkv_lin, bkv_lin, wk, bk, wv, bv, weffp,
                                   beff);
  k_hist<<<(E + 255) / 256, 256, 0, stream>>>(dst, rs, E);
  k_scan<<<1, 1024, 0, stream>>>(rs, cur, D);
  k_scatter<<<(E + 255) / 256, 256, 0, stream>>>(dst, cur, csr, dstc, E);
  k_q<<<(D + 63) / 64, 512, 0, stream>>>(h, bqe, bq, bk, bv, wq1, w3, qhd, khs,
                                         vhs, D);
  k_kv<<<(E + 127) / 128, 1024, 0, stream>>>(h, f, dt, weffp, beff, csr, dstc,
                                             qhd, att, vhg, D, E);
  k_agg<<<(D + 3) / 4, 256, 0, stream>>>(qhd, khs, vhs, att, vhg, rs, lng, lnb,
                                         out, D);
}